// Round 4
// baseline (801.185 us; speedup 1.0000x reference)
//
#include <hip/hip_runtime.h>
#include <hip/hip_bf16.h>

// Problem: B=32, S=1024, D=1024, dm=1024, 16 heads x 64
#define DM 1024
#define NB 32

typedef __bf16 bf16_t;
typedef __attribute__((ext_vector_type(8))) __bf16 bf16x8;
typedef __attribute__((ext_vector_type(4))) float  f32x4;

__device__ inline float bf2f(bf16_t v) {
    union { unsigned short s; __bf16 b; } u; u.b = v;
    union { unsigned int i; float f; } w; w.i = ((unsigned int)u.s) << 16;
    return w.f;
}
__device__ inline bf16_t f2bf(float f) {
    union { unsigned int i; float f; } w; w.f = f;
    unsigned int r = (w.i + 0x7FFFu + ((w.i >> 16) & 1u)) >> 16;
    union { unsigned short s; __bf16 b; } u; u.s = (unsigned short)r;
    return u.b;
}

enum EpiMode { EPI_NONE = 0, EPI_BIAS_ROW = 1, EPI_BIAS_COL = 2, EPI_SCALE = 3 };

// ---- dtype probe: mode=1 if x is fp32, mode=0 if bf16 ----
// True bf16 N(0,1) data: |v| < 2^14 always -> 0 hits. fp32 data read as
// 16-bit words: even words are random mantissa bits -> exp-field >= 0x8D
// with p~0.45 -> ~900 hits out of 2048. Threshold 16 separates by >50 sigma.
__global__ void detect_mode(const unsigned short* __restrict__ x, int* __restrict__ mode)
{
    if (threadIdx.x == 0 && blockIdx.x == 0) {
        int hits = 0;
        for (int i = 0; i < 2048; ++i) {
            unsigned e = (x[i] >> 7) & 0xFFu;
            hits += (e >= 0x8Du) ? 1 : 0;
        }
        *mode = (hits >= 16) ? 1 : 0;
    }
}

// ---- convert x (elements [off, off+n8*8)) to bf16 ----
__global__ void convert_x(const void* __restrict__ xin, bf16_t* __restrict__ xb,
                          const int* __restrict__ modep, long long off, long long n8)
{
    const long long i = (long long)blockIdx.x * blockDim.x + threadIdx.x;
    if (i >= n8) return;
    bf16x8 o;
    if (*modep) {
        const float* s = (const float*)xin + off + i * 8;
#pragma unroll
        for (int j = 0; j < 8; ++j) o[j] = f2bf(s[j]);
    } else {
        o = *(const bf16x8*)((const bf16_t*)xin + off + i * 8);
    }
    *(bf16x8*)(xb + i * 8) = o;
}

// ---- transpose the three weight matrices -> bf16 Wt[n][k] = W[k][n] ----
__global__ void transpose3(const void* __restrict__ Wq, const void* __restrict__ Wk,
                           const void* __restrict__ Wv, bf16_t* __restrict__ Wt,
                           const int* __restrict__ modep)
{
    const int md = *modep;
    const void* src = (blockIdx.z == 0) ? Wq : (blockIdx.z == 1) ? Wk : Wv;
    bf16_t* dst = Wt + (size_t)blockIdx.z * DM * DM;
    __shared__ bf16_t T[64][72];
    const int tid = threadIdx.x;
    const int r  = tid >> 2;   // 0..63
    const int cp = tid & 3;    // 16 elems each
    const int r0 = blockIdx.y * 64;  // k block
    const int c0 = blockIdx.x * 64;  // n block
    const size_t base = (size_t)(r0 + r) * DM + c0 + cp * 16;
    bf16_t tmp[16];
    if (md) {
        const float* s = (const float*)src + base;
#pragma unroll
        for (int j = 0; j < 16; ++j) tmp[j] = f2bf(s[j]);
    } else {
        const bf16_t* s = (const bf16_t*)src + base;
        bf16x8 a = *(const bf16x8*)s;
        bf16x8 b = *(const bf16x8*)(s + 8);
#pragma unroll
        for (int j = 0; j < 8; ++j) { tmp[j] = a[j]; tmp[8 + j] = b[j]; }
    }
#pragma unroll
    for (int j = 0; j < 16; ++j) T[cp * 16 + j][r] = tmp[j];
    __syncthreads();
    bf16_t* d = dst + (size_t)(c0 + r) * DM + r0 + cp * 16;
    bf16x8 w0, w1;
#pragma unroll
    for (int j = 0; j < 8; ++j) w0[j] = T[r][cp * 16 + j];
#pragma unroll
    for (int j = 0; j < 8; ++j) w1[j] = T[r][cp * 16 + 8 + j];
    *(bf16x8*)d = w0;
    *(bf16x8*)(d + 8) = w1;
}

// NT gemm: C[M,N] = A[M,K] * B[N,K]^T, bf16 in, fp32 accum.
// Tile 128x128, BK=64, 256 threads (4 waves 2x2, 4x4 mfma 16x16x32 each).
// CONSERVATIVE staging this round (diagnostic): global b128 loads -> VGPR
// -> ds_write_b128, prefetched one iteration ahead (m93 structure).
template <int MODE, bool DUALOUT>
__global__ __launch_bounds__(256, 2)
void gemm_nt(const bf16_t* __restrict__ A, long long sA,
             const bf16_t* __restrict__ B, long long sB,
             void* __restrict__ C, long long sC, long long cOff,
             const void* __restrict__ bias, const int* __restrict__ modep,
             int M, int N, int K, float scale)
{
    constexpr int BM = 128, BN = 128, BK = 64;
    __shared__ __align__(16) bf16_t As[BM * BK];
    __shared__ __align__(16) bf16_t Bs[BN * BK];

    const int z = blockIdx.z;
    const bf16_t* Ab = A + (size_t)z * (size_t)sA;
    const bf16_t* Bb = B + (size_t)z * (size_t)sB;

    const int gm0 = blockIdx.y * BM;
    const int gn0 = blockIdx.x * BN;

    const int tid  = threadIdx.x;
    const int wave = tid >> 6;
    const int lane = tid & 63;
    const int wm   = (wave >> 1) * 64;
    const int wn   = (wave & 1) * 64;
    const int lm   = lane & 15;
    const int quad = lane >> 4;

    f32x4 acc[4][4];
#pragma unroll
    for (int i = 0; i < 4; ++i)
#pragma unroll
        for (int j = 0; j < 4; ++j) acc[i][j] = (f32x4)0.0f;

    const int nIter = K / BK;
    bf16x8 rA[4], rB[4];

    // chunk ch = tid + i*256; row = ch>>3 (0..127), kc = ch&7 (16B chunks)
    auto gload = [&](int it) {
#pragma unroll
        for (int i = 0; i < 4; ++i) {
            const int ch = tid + i * 256;
            const int row = ch >> 3, kc = ch & 7;
            rA[i] = *(const bf16x8*)(Ab + (size_t)(gm0 + row) * K + it * BK + kc * 8);
            rB[i] = *(const bf16x8*)(Bb + (size_t)(gn0 + row) * K + it * BK + kc * 8);
        }
    };
    auto swrite = [&]() {
#pragma unroll
        for (int i = 0; i < 4; ++i) {
            const int ch = tid + i * 256;
            const int row = ch >> 3, kc = ch & 7;
            *(bf16x8*)&As[row * BK + kc * 8] = rA[i];
            *(bf16x8*)&Bs[row * BK + kc * 8] = rB[i];
        }
    };

    gload(0);

    for (int it = 0; it < nIter; ++it) {
        __syncthreads();          // prior iter's LDS reads done before overwrite
        swrite();
        __syncthreads();          // LDS visible to all waves
        if (it + 1 < nIter) gload(it + 1);   // prefetch overlaps compute
#pragma unroll
        for (int kh = 0; kh < 2; ++kh) {
            bf16x8 af[4], bg[4];
#pragma unroll
            for (int mt = 0; mt < 4; ++mt) {
                const int m = wm + mt * 16 + lm;
                af[mt] = *(const bf16x8*)&As[m * BK + (kh * 4 + quad) * 8];
            }
#pragma unroll
            for (int nt = 0; nt < 4; ++nt) {
                const int n = wn + nt * 16 + lm;
                bg[nt] = *(const bf16x8*)&Bs[n * BK + (kh * 4 + quad) * 8];
            }
#pragma unroll
            for (int mt = 0; mt < 4; ++mt)
#pragma unroll
                for (int nt = 0; nt < 4; ++nt)
                    acc[mt][nt] = __builtin_amdgcn_mfma_f32_16x16x32_bf16(
                        af[mt], bg[nt], acc[mt][nt], 0, 0, 0);
        }
    }

    // epilogue: C/D layout col=lane&15, row=quad*4+r (m89/m91-verified)
    const int md = *modep;
#pragma unroll
    for (int mt = 0; mt < 4; ++mt) {
        float rbias[4];
        if (MODE == EPI_BIAS_ROW) {
#pragma unroll
            for (int r = 0; r < 4; ++r) {
                const int i = gm0 + wm + mt * 16 + quad * 4 + r;
                rbias[r] = md ? ((const float*)bias)[i] : bf2f(((const bf16_t*)bias)[i]);
            }
        }
#pragma unroll
        for (int nt = 0; nt < 4; ++nt) {
            const int col = gn0 + wn + nt * 16 + lm;
            float cbias = 0.f;
            if (MODE == EPI_BIAS_COL)
                cbias = md ? ((const float*)bias)[col] : bf2f(((const bf16_t*)bias)[col]);
#pragma unroll
            for (int r = 0; r < 4; ++r) {
                const int row = gm0 + wm + mt * 16 + quad * 4 + r;
                float v = acc[mt][nt][r];
                if (MODE == EPI_BIAS_ROW) v += rbias[r];
                if (MODE == EPI_BIAS_COL) v += cbias;
                if (MODE == EPI_SCALE)    v *= scale;
                const size_t off = (size_t)cOff + (size_t)z * sC + (size_t)row * N + col;
                if (DUALOUT && md) ((float*)C)[off] = v;
                else               ((bf16_t*)C)[off] = f2bf(v);
            }
        }
    }
}

// In-place chunked softmax + transpose on Y[zb][DM][DM] (bf16 internal):
// Y <- Yt with Yt[b][e][d] = softmax_64chunk(Y[b][d][:])[e]. Softmax axis is
// tile-aligned, so tile (I,J) softmaxes locally and swaps with (J,I);
// disjoint pairs across blocks -> race-free.
__global__ void softmax_t_inplace(bf16_t* __restrict__ Y)
{
    const int b = blockIdx.z;
    int idx = blockIdx.x;           // 0..135
    int I = 0;
    while (idx >= 16 - I) { idx -= 16 - I; ++I; }
    const int J = I + idx;

    const int tid = threadIdx.x;
    const int r  = tid >> 2;
    const int cp = tid & 3;

    bf16_t* base = Y + ((size_t)b << 20);
    bf16_t* t0 = base + (size_t)(I * 64 + r) * DM + J * 64 + cp * 16;
    bf16_t* t1 = base + (size_t)(J * 64 + r) * DM + I * 64 + cp * 16;

    __shared__ bf16_t P0[64][72];
    __shared__ bf16_t P1[64][72];

    bf16x8 a0 = *(const bf16x8*)t0;
    bf16x8 a1 = *(const bf16x8*)(t0 + 8);
    bf16x8 c0v, c1v;
    if (J != I) { c0v = *(const bf16x8*)t1; c1v = *(const bf16x8*)(t1 + 8); }

    {
        float f[16];
#pragma unroll
        for (int j = 0; j < 8; ++j) f[j] = bf2f(a0[j]);
#pragma unroll
        for (int j = 0; j < 8; ++j) f[8 + j] = bf2f(a1[j]);
        float m = -1e30f;
#pragma unroll
        for (int j = 0; j < 16; ++j) m = fmaxf(m, f[j]);
        m = fmaxf(m, __shfl_xor(m, 1));
        m = fmaxf(m, __shfl_xor(m, 2));
        float s = 0.f;
#pragma unroll
        for (int j = 0; j < 16; ++j) { f[j] = __expf(f[j] - m); s += f[j]; }
        s += __shfl_xor(s, 1);
        s += __shfl_xor(s, 2);
        const float inv = 1.0f / s;
#pragma unroll
        for (int j = 0; j < 16; ++j) P0[cp * 16 + j][r] = f2bf(f[j] * inv);
    }
    if (J != I) {
        float f[16];
#pragma unroll
        for (int j = 0; j < 8; ++j) f[j] = bf2f(c0v[j]);
#pragma unroll
        for (int j = 0; j < 8; ++j) f[8 + j] = bf2f(c1v[j]);
        float m = -1e30f;
#pragma unroll
        for (int j = 0; j < 16; ++j) m = fmaxf(m, f[j]);
        m = fmaxf(m, __shfl_xor(m, 1));
        m = fmaxf(m, __shfl_xor(m, 2));
        float s = 0.f;
#pragma unroll
        for (int j = 0; j < 16; ++j) { f[j] = __expf(f[j] - m); s += f[j]; }
        s += __shfl_xor(s, 1);
        s += __shfl_xor(s, 2);
        const float inv = 1.0f / s;
#pragma unroll
        for (int j = 0; j < 16; ++j) P1[cp * 16 + j][r] = f2bf(f[j] * inv);
    }
    __syncthreads();

    bf16x8 w0, w1;
#pragma unroll
    for (int j = 0; j < 8; ++j) w0[j] = P0[r][cp * 16 + j];
#pragma unroll
    for (int j = 0; j < 8; ++j) w1[j] = P0[r][cp * 16 + 8 + j];
    *(bf16x8*)t1 = w0;
    *(bf16x8*)(t1 + 8) = w1;
    if (J != I) {
#pragma unroll
        for (int j = 0; j < 8; ++j) w0[j] = P1[r][cp * 16 + j];
#pragma unroll
        for (int j = 0; j < 8; ++j) w1[j] = P1[r][cp * 16 + 8 + j];
        *(bf16x8*)t0 = w0;
        *(bf16x8*)(t0 + 8) = w1;
    }
}

extern "C" void kernel_launch(void* const* d_in, const int* in_sizes, int n_in,
                              void* d_out, int out_size, void* d_ws, size_t ws_size,
                              hipStream_t stream)
{
    const void* x  = d_in[0];
    const void* Wq = d_in[1];
    const void* bq = d_in[2];
    const void* Wk = d_in[3];
    const void* bk = d_in[4];
    const void* Wv = d_in[5];
    const void* bv = d_in[6];

    // ws layout: [mode int | pad to 256] [Wt 6MB] [xb CB] [qt CB] [kt CB] [y CB]
    // per-CB slabs are 2MB each; CB adaptive to ws_size (fixed per session).
    char* ws = (char*)d_ws;
    int* mode = (int*)ws;
    const size_t MB2 = (size_t)DM * DM * 2;
    const size_t hdr = 256;
    int CB = NB;
    while (CB > 1 && hdr + 3 * MB2 + 4 * (size_t)CB * MB2 > ws_size) CB >>= 1;

    bf16_t* Wt = (bf16_t*)(ws + hdr);
    bf16_t* xb = (bf16_t*)(ws + hdr + 3 * MB2);
    bf16_t* qt = xb + (size_t)CB * DM * DM;
    bf16_t* kt = qt + (size_t)CB * DM * DM;
    bf16_t* y  = kt + (size_t)CB * DM * DM;
    bf16_t* v  = qt;   // qt dead after QK^T; reuse for V

    detect_mode<<<1, 64, 0, stream>>>((const unsigned short*)x, mode);
    transpose3<<<dim3(16, 16, 3), 256, 0, stream>>>(Wq, Wk, Wv, Wt, mode);

    const long long msz = (long long)DM * DM;
    for (int c = 0; c < NB; c += CB) {
        const int zb = (NB - c < CB) ? (NB - c) : CB;
        const long long n8 = (long long)zb * msz / 8;
        convert_x<<<(int)((n8 + 255) / 256), 256, 0, stream>>>(x, xb, mode, (long long)c * msz, n8);

        const dim3 g(8, 8, zb), blk(256);
        // qt[b][d][s] = Wq^T x^T + bq (row bias)
        gemm_nt<EPI_BIAS_ROW, false><<<g, blk, 0, stream>>>(Wt, 0, xb, msz, qt, msz, 0, bq, mode, DM, DM, DM, 1.f);
        // kt[b][e][s]
        gemm_nt<EPI_BIAS_ROW, false><<<g, blk, 0, stream>>>(Wt + msz, 0, xb, msz, kt, msz, 0, bk, mode, DM, DM, DM, 1.f);
        // y[b][d][e] = qt . kt / 8
        gemm_nt<EPI_SCALE, false><<<g, blk, 0, stream>>>(qt, msz, kt, msz, y, msz, 0, nullptr, mode, DM, DM, DM, 0.125f);
        // y <- softmax+transpose in place
        softmax_t_inplace<<<dim3(136, 1, zb), 256, 0, stream>>>(y);
        // v[b][s][d] = x Wv^T + bv (col bias) -> qt slab
        gemm_nt<EPI_BIAS_COL, false><<<g, blk, 0, stream>>>(xb, msz, Wt + 2 * msz, 0, v, msz, 0, bv, mode, DM, DM, DM, 1.f);
        // out[b][s][e] = v . y   (dual-dtype output)
        gemm_nt<EPI_NONE, true><<<g, blk, 0, stream>>>(v, msz, y, msz, d_out, msz, (long long)c * msz, nullptr, mode, DM, DM, DM, 1.f);
    }
}